// Round 8
// baseline (404.763 us; speedup 1.0000x reference)
//
#include <hip/hip_runtime.h>
#include <hip/hip_cooperative_groups.h>
#include <hip/hip_bf16.h>
#include <math.h>

namespace cg = cooperative_groups;

typedef short v8s __attribute__((ext_vector_type(8)));
typedef float v4f __attribute__((ext_vector_type(4)));

#define NH 12
#define DS 384

static __device__ __forceinline__ ushort f2bf(float f) {
    __hip_bfloat16 h = __float2bfloat16(f);
    return *reinterpret_cast<ushort*>(&h);
}
static __device__ __forceinline__ float bf2f(ushort u) {
    return __uint_as_float(((unsigned)u) << 16);
}
static __device__ __forceinline__ float gelu_exact(float x) {
    return 0.5f * x * (1.0f + erff(x * 0.70710678118654752f));
}

struct MegaArgs {
    const float *s, *pair, *g_s, *b_s, *Wq, *Wk, *Wv, *Wb, *Wo, *bo, *g_f, *b_f, *W1, *b1, *W2, *b2;
    float* out;
    ushort* Opart; float* mlb; float* s1; ushort* qkv; ushort* sn;
    ushort* attb; ushort* t1; ushort* qkvT; ushort* WoT; ushort* W1T; ushort* W2T;
};

// register-resident bf16 MFMA GEMM 64x64 block-tile (256 thr, 4 waves 2x2)
// EPI: 4 = bf16 store ; 5 = f32 atomicAdd
static __device__ __forceinline__ void mgemm_body(const ushort* Aa, const ushort* BT,
                                                  float* Cf, ushort* Cb,
                                                  int m0, int n0, int K, int ldc,
                                                  int kbeg, int kend, int EPI, int tid) {
    const int w = tid >> 6, lane = tid & 63;
    const int c = lane & 15, g = lane >> 4;
    const int mq = m0 + (w >> 1) * 32;
    const int nq = n0 + (w & 1) * 32;

    v4f acc[2][2];
#pragma unroll
    for (int i = 0; i < 2; ++i)
#pragma unroll
        for (int j = 0; j < 2; ++j) acc[i][j] = (v4f){0.f, 0.f, 0.f, 0.f};

    const ushort* Ap0 = Aa + (long)(mq + c) * K + g * 8;
    const ushort* Ap1 = Aa + (long)(mq + 16 + c) * K + g * 8;
    const ushort* Bp0 = BT + (long)(nq + c) * K + g * 8;
    const ushort* Bp1 = BT + (long)(nq + 16 + c) * K + g * 8;

#pragma unroll 4
    for (int k0 = kbeg; k0 < kend; k0 += 32) {
        v8s a0 = *reinterpret_cast<const v8s*>(Ap0 + k0);
        v8s a1 = *reinterpret_cast<const v8s*>(Ap1 + k0);
        v8s b0 = *reinterpret_cast<const v8s*>(Bp0 + k0);
        v8s b1 = *reinterpret_cast<const v8s*>(Bp1 + k0);
        acc[0][0] = __builtin_amdgcn_mfma_f32_16x16x32_bf16(a0, b0, acc[0][0], 0, 0, 0);
        acc[0][1] = __builtin_amdgcn_mfma_f32_16x16x32_bf16(a0, b1, acc[0][1], 0, 0, 0);
        acc[1][0] = __builtin_amdgcn_mfma_f32_16x16x32_bf16(a1, b0, acc[1][0], 0, 0, 0);
        acc[1][1] = __builtin_amdgcn_mfma_f32_16x16x32_bf16(a1, b1, acc[1][1], 0, 0, 0);
    }

#pragma unroll
    for (int mi = 0; mi < 2; ++mi) {
#pragma unroll
        for (int ni = 0; ni < 2; ++ni) {
#pragma unroll
            for (int r = 0; r < 4; ++r) {
                const int row = mq + mi * 16 + g * 4 + r;
                const int col = nq + ni * 16 + c;
                const long idx = (long)row * ldc + col;
                if (EPI == 4) Cb[idx] = f2bf(acc[mi][ni][r]);
                else atomicAdd(&Cf[idx], acc[mi][ni][r]);
            }
        }
    }
}

__global__ __launch_bounds__(256, 1) void mega_k(MegaArgs A) {
    // LDS budget (static): 32768 + 49152 + 5120 + 50176 + 4224 = 141440 B  (<160 KiB, 1 block/CU)
    __shared__ float  Stage[4][2048];       // fa2: per-wave 8 KB pair stage
    __shared__ ushort BLs[4][16 * 32 * NH]; // fa2: per-wave bias tile [qrow][key][head]
    __shared__ ushort Ps[4][16 * 40];       // fa2: per-wave P tile (stride 40 = 16B aligned rows)
    __shared__ ushort Abuf[64][392];        // w1ln LN-ed A tile
    __shared__ float  tile[32][33];         // wcvt transpose tile

    cg::grid_group grid = cg::this_grid();
    const int bid = blockIdx.x;
    const int tid = threadIdx.x;

    // ================= P0: weight cvts [0,1728) + LN1 [1728,1984) + s1=s+bo [1984,2368) =================
    for (int vb = bid; vb < 2368; vb += 256) {
        __syncthreads();
        if (vb < 1728) {
            int id = vb;
            const float* W; ushort* WT; int Kd, Nd, t;
            if (id < 144)       { W = A.Wq; WT = A.qkvT;             Kd = 384;  Nd = 384;  t = id; }
            else if (id < 288)  { W = A.Wk; WT = A.qkvT + 384 * 384; Kd = 384;  Nd = 384;  t = id - 144; }
            else if (id < 432)  { W = A.Wv; WT = A.qkvT + 768 * 384; Kd = 384;  Nd = 384;  t = id - 288; }
            else if (id < 576)  { W = A.Wo; WT = A.WoT;              Kd = 384;  Nd = 384;  t = id - 432; }
            else if (id < 1152) { W = A.W1; WT = A.W1T;              Kd = 384;  Nd = 1536; t = id - 576; }
            else                { W = A.W2; WT = A.W2T;              Kd = 1536; Nd = 384;  t = id - 1152; }
            const int ktiles = Kd >> 5;
            const int k0 = (t % ktiles) * 32, n0 = (t / ktiles) * 32;
            const int r = tid >> 3, c4 = (tid & 7) * 4;
            float4 v = *reinterpret_cast<const float4*>(W + (long)(k0 + r) * Nd + n0 + c4);
            tile[r][c4 + 0] = v.x; tile[r][c4 + 1] = v.y;
            tile[r][c4 + 2] = v.z; tile[r][c4 + 3] = v.w;
            __syncthreads();
            ushort4 o;
            o.x = f2bf(tile[c4 + 0][r]); o.y = f2bf(tile[c4 + 1][r]);
            o.z = f2bf(tile[c4 + 2][r]); o.w = f2bf(tile[c4 + 3][r]);
            *reinterpret_cast<ushort4*>(WT + (long)(n0 + r) * Kd + k0 + c4) = o;
        } else if (vb < 1984) {
            const int wid = tid >> 6, lane = tid & 63;
            const int row = (vb - 1728) * 4 + wid;
            const float* xr = A.s + (long)row * DS;
            float v[6];
            float sm = 0.f;
#pragma unroll
            for (int t = 0; t < 6; ++t) { v[t] = xr[lane + t * 64]; sm += v[t]; }
#pragma unroll
            for (int o = 32; o >= 1; o >>= 1) sm += __shfl_xor(sm, o);
            const float mean = sm * (1.f / DS);
            float q = 0.f;
#pragma unroll
            for (int t = 0; t < 6; ++t) { float d = v[t] - mean; q += d * d; }
#pragma unroll
            for (int o = 32; o >= 1; o >>= 1) q += __shfl_xor(q, o);
            const float rs = rsqrtf(q * (1.f / DS) + 1e-5f);
#pragma unroll
            for (int t = 0; t < 6; ++t) {
                int cc = lane + t * 64;
                A.sn[(long)row * DS + cc] = f2bf((v[t] - mean) * rs * A.g_s[cc] + A.b_s[cc]);
            }
        } else {
            const int i4 = ((vb - 1984) * 256 + tid) * 4;
            float4 sv = *reinterpret_cast<const float4*>(A.s + i4);
            const int col = i4 % DS;
            float4 bv = *reinterpret_cast<const float4*>(A.bo + col);
            float4 o;
            o.x = sv.x + bv.x; o.y = sv.y + bv.y;
            o.z = sv.z + bv.z; o.w = sv.w + bv.w;
            *reinterpret_cast<float4*>(A.s1 + i4) = o;
        }
    }
    grid.sync();

    // ================= P1: QKV GEMM -> qkv bf16 [1024][1152] =================
    for (int vb = bid; vb < 288; vb += 256)
        mgemm_body(A.sn, A.qkvT, nullptr, A.qkv,
                   (vb % 16) * 64, (vb / 16) * 64, 384, 1152, 0, 384, 4, tid);
    grid.sync();

    // ================= P2: fused pair-bias + attention chunks (wave-local) =================
    {
        const int w4 = tid >> 6, lane = tid & 63;
        const int c = lane & 15, g = lane >> 4;
        const float scale = 0.17677669529663688f;
        float* stagew = Stage[w4];
        ushort* BLw = BLs[w4];
        ushort* Pw = Ps[w4];

        // Wb fragments (proven pairb layout)
        v8s bfrag[4];
#pragma unroll
        for (int t2 = 0; t2 < 4; ++t2) {
#pragma unroll
            for (int j = 0; j < 8; ++j) {
                int p = t2 * 32 + g * 8 + j;
                float wv = (c < NH) ? A.Wb[p * NH + c] : 0.f;
                bfrag[t2][j] = (short)f2bf(wv);
            }
        }
        const int xorkey = (c & 7) << 4;
        const int gw = bid * 4 + w4;   // 0..1023

#pragma unroll 1
        for (int i = 0; i < 2; ++i) {
            const int u = gw + i * 1024;          // 0..2047, bijective
            const int kc = u & 31;
            const int qb = (u >> 5) & 31;
            const int wu = u >> 10;
            const int q0w = qb * 32 + wu * 16;    // this wave-unit's 16 q rows
            const int k0 = kc * 32;

            // ---- phase 1: 32 tiles of (1 q row x 16 keys x 128 feats = 8 KB) ----
#pragma unroll 1
            for (int t = 0; t < 32; ++t) {
                const int ql = t >> 1, kh = t & 1;
                const long tb = ((long)(q0w + ql) * 1024 + k0 + kh * 16) * 128;
                asm volatile("s_waitcnt lgkmcnt(0)" ::: "memory");
#pragma unroll
                for (int j = 0; j < 8; ++j) {
                    const int doff = j * 1024 + lane * 16;
                    const int loff = doff ^ ((((doff >> 9) & 7)) << 4);
                    __builtin_amdgcn_global_load_lds(
                        (const __attribute__((address_space(1))) void*)((const char*)(A.pair + tb) + loff),
                        (__attribute__((address_space(3))) void*)(&stagew[j * 256]),
                        16, 0, 0);
                }
                asm volatile("s_waitcnt vmcnt(0)" ::: "memory");

                const char* sw = (const char*)stagew;
                v4f acc = {0.f, 0.f, 0.f, 0.f};
#pragma unroll
                for (int t2 = 0; t2 < 4; ++t2) {
                    const int lo = c * 512 + t2 * 128 + g * 32;
                    v4f x0 = *reinterpret_cast<const v4f*>(sw + (lo ^ xorkey));
                    v4f x1 = *reinterpret_cast<const v4f*>(sw + ((lo + 16) ^ xorkey));
                    v8s a;
                    a[0] = (short)f2bf(x0[0]); a[1] = (short)f2bf(x0[1]);
                    a[2] = (short)f2bf(x0[2]); a[3] = (short)f2bf(x0[3]);
                    a[4] = (short)f2bf(x1[0]); a[5] = (short)f2bf(x1[1]);
                    a[6] = (short)f2bf(x1[2]); a[7] = (short)f2bf(x1[3]);
                    acc = __builtin_amdgcn_mfma_f32_16x16x32_bf16(a, bfrag[t2], acc, 0, 0, 0);
                }
                if (c < NH) {
#pragma unroll
                    for (int r = 0; r < 4; ++r)
                        BLw[(ql * 32 + kh * 16 + g * 4 + r) * NH + c] = f2bf(acc[r]);
                }
            }

            // ---- phase 2: per-head QK^T + bias, max-free exp, PV ----
#pragma unroll 1
            for (int h = 0; h < NH; ++h) {
                const v8s aq = *reinterpret_cast<const v8s*>(
                    A.qkv + (long)(q0w + c) * 1152 + h * 32 + g * 8);

                v4f sfr[2];
#pragma unroll
                for (int nf = 0; nf < 2; ++nf) {
                    v8s bk = *reinterpret_cast<const v8s*>(
                        A.qkv + (long)(k0 + nf * 16 + c) * 1152 + 384 + h * 32 + g * 8);
                    v4f z = {0.f, 0.f, 0.f, 0.f};
                    sfr[nf] = __builtin_amdgcn_mfma_f32_16x16x32_bf16(aq, bk, z, 0, 0, 0);
                }

                float p[2][4];
                float ls[4];
#pragma unroll
                for (int r = 0; r < 4; ++r) ls[r] = 0.f;
#pragma unroll
                for (int nf = 0; nf < 2; ++nf) {
#pragma unroll
                    for (int r = 0; r < 4; ++r) {
                        const int qr = g * 4 + r;
                        float sv = sfr[nf][r] * scale + bf2f(BLw[(qr * 32 + nf * 16 + c) * NH + h]);
                        float e = __expf(sv);
                        p[nf][r] = e;
                        ls[r] += e;
                    }
                }
#pragma unroll
                for (int r = 0; r < 4; ++r) {
                    ls[r] += __shfl_xor(ls[r], 1);
                    ls[r] += __shfl_xor(ls[r], 2);
                    ls[r] += __shfl_xor(ls[r], 4);
                    ls[r] += __shfl_xor(ls[r], 8);
                }

#pragma unroll
                for (int nf = 0; nf < 2; ++nf)
#pragma unroll
                    for (int r = 0; r < 4; ++r)
                        Pw[(g * 4 + r) * 40 + nf * 16 + c] = f2bf(p[nf][r]);

                const v8s pa = *reinterpret_cast<const v8s*>(&Pw[c * 40 + g * 8]);

                v4f oacc[2];
#pragma unroll
                for (int nf2 = 0; nf2 < 2; ++nf2) {
                    v8s vbt;
#pragma unroll
                    for (int j = 0; j < 8; ++j)
                        vbt[j] = (short)A.qkv[(long)(k0 + g * 8 + j) * 1152 + 768 + h * 32 + nf2 * 16 + c];
                    v4f z = {0.f, 0.f, 0.f, 0.f};
                    oacc[nf2] = __builtin_amdgcn_mfma_f32_16x16x32_bf16(pa, vbt, z, 0, 0, 0);
                }

                const long base = ((long)(h * 32 + kc) * 1024 + q0w + g * 4);
#pragma unroll
                for (int r = 0; r < 4; ++r) {
                    A.Opart[(base + r) * 32 + c] = f2bf(oacc[0][r]);
                    A.Opart[(base + r) * 32 + 16 + c] = f2bf(oacc[1][r]);
                }
                if (c == 0) {
#pragma unroll
                    for (int r = 0; r < 4; ++r)
                        A.mlb[base + r] = ls[r];
                }
            }
        }
    }
    grid.sync();

    // ================= P3: combine chunks -> attb =================
    for (int vb = bid; vb < 192; vb += 256) {
        const int h = vb / 16;
        const int q = (vb % 16) * 64 + (tid >> 2);
        const int ds = (tid & 3) * 8;

        float lsum = 0.f;
        float O[8];
#pragma unroll
        for (int j = 0; j < 8; ++j) O[j] = 0.f;

        for (int kc = 0; kc < 32; ++kc) {
            const long base = ((long)(h * 32 + kc) * 1024 + q);
            lsum += A.mlb[base];
            v8s ov = *reinterpret_cast<const v8s*>(A.Opart + base * 32 + ds);
#pragma unroll
            for (int j = 0; j < 8; ++j) O[j] += bf2f((ushort)ov[j]);
        }
        const float inv = 1.f / lsum;
        ushort4 u0, u1;
        u0.x = f2bf(O[0] * inv); u0.y = f2bf(O[1] * inv);
        u0.z = f2bf(O[2] * inv); u0.w = f2bf(O[3] * inv);
        u1.x = f2bf(O[4] * inv); u1.y = f2bf(O[5] * inv);
        u1.z = f2bf(O[6] * inv); u1.w = f2bf(O[7] * inv);
        *reinterpret_cast<ushort4*>(A.attb + (long)q * DS + h * 32 + ds) = u0;
        *reinterpret_cast<ushort4*>(A.attb + (long)q * DS + h * 32 + ds + 4) = u1;
    }
    grid.sync();

    // ================= P4: s1 += attb @ Wo (split-K=4, atomic; s1 pre-init = s + bo) =================
    for (int vb = bid; vb < 384; vb += 256) {
        const int z = vb / 96;
        mgemm_body(A.attb, A.WoT, A.s1, nullptr,
                   (vb % 16) * 64, ((vb / 16) % 6) * 64, 384, 384, z * 96, z * 96 + 96, 5, tid);
    }
    grid.sync();

    // ================= P5: t1 = gelu(LN(s1) @ W1 + b1) ; ny==0 also writes out = s1 + b2 =================
    for (int vb = bid; vb < 384; vb += 256) {
        __syncthreads();
        const int m0 = (vb % 16) * 64;
        const int ny = vb / 16;
        const int n0 = ny * 64;
        {
            const int row = tid >> 2, part = tid & 3;
            const float* xr = A.s1 + (long)(m0 + row) * DS + part * 96;
            float sum = 0.f, sq = 0.f;
#pragma unroll
            for (int i = 0; i < 24; ++i) {
                float4 v = *reinterpret_cast<const float4*>(xr + i * 4);
                sum += v.x + v.y + v.z + v.w;
                sq += v.x * v.x + v.y * v.y + v.z * v.z + v.w * v.w;
            }
            sum += __shfl_xor(sum, 1); sum += __shfl_xor(sum, 2);
            sq  += __shfl_xor(sq, 1);  sq  += __shfl_xor(sq, 2);
            const float mean = sum * (1.f / DS);
            const float var = sq * (1.f / DS) - mean * mean;
            const float rs = rsqrtf(var + 1e-5f);
#pragma unroll
            for (int i = 0; i < 24; ++i) {
                float4 v = *reinterpret_cast<const float4*>(xr + i * 4);
                const int col = part * 96 + i * 4;
                float4 gv = *reinterpret_cast<const float4*>(A.g_f + col);
                float4 bv = *reinterpret_cast<const float4*>(A.b_f + col);
                ushort4 o;
                o.x = f2bf((v.x - mean) * rs * gv.x + bv.x);
                o.y = f2bf((v.y - mean) * rs * gv.y + bv.y);
                o.z = f2bf((v.z - mean) * rs * gv.z + bv.z);
                o.w = f2bf((v.w - mean) * rs * gv.w + bv.w);
                *reinterpret_cast<ushort4*>(&Abuf[row][col]) = o;
                if (ny == 0) {
                    float4 b2v = *reinterpret_cast<const float4*>(A.b2 + col);
                    float4 ov;
                    ov.x = v.x + b2v.x; ov.y = v.y + b2v.y;
                    ov.z = v.z + b2v.z; ov.w = v.w + b2v.w;
                    *reinterpret_cast<float4*>(A.out + (long)(m0 + row) * DS + col) = ov;
                }
            }
        }
        __syncthreads();

        const int w = tid >> 6, lane = tid & 63;
        const int c = lane & 15, g = lane >> 4;
        const int mloc = (w >> 1) * 32;
        const int nloc = n0 + (w & 1) * 32;

        v4f acc[2][2];
#pragma unroll
        for (int i = 0; i < 2; ++i)
#pragma unroll
            for (int j = 0; j < 2; ++j) acc[i][j] = (v4f){0.f, 0.f, 0.f, 0.f};

        const ushort* Bp0 = A.W1T + (long)(nloc + c) * 384 + g * 8;
        const ushort* Bp1 = A.W1T + (long)(nloc + 16 + c) * 384 + g * 8;

#pragma unroll 4
        for (int k0 = 0; k0 < 384; k0 += 32) {
            v8s a0 = *reinterpret_cast<const v8s*>(&Abuf[mloc + c][k0 + g * 8]);
            v8s a1 = *reinterpret_cast<const v8s*>(&Abuf[mloc + 16 + c][k0 + g * 8]);
            v8s b0 = *reinterpret_cast<const v8s*>(Bp0 + k0);
            v8s b1 = *reinterpret_cast<const v8s*>(Bp1 + k0);
            acc[0][0] = __builtin_amdgcn_mfma_f32_16x16x32_bf16(a0, b0, acc[0][0], 0, 0, 0);
            acc[0][1] = __builtin_amdgcn_mfma_f32_16x16x32_bf16(a0, b1, acc[0][1], 0, 0, 0);
            acc[1][0] = __builtin_amdgcn_mfma_f32_16x16x32_bf16(a1, b0, acc[1][0], 0, 0, 0);
            acc[1][1] = __builtin_amdgcn_mfma_f32_16x16x32_bf16(a1, b1, acc[1][1], 0, 0, 0);
        }

#pragma unroll
        for (int mi = 0; mi < 2; ++mi) {
#pragma unroll
            for (int ni = 0; ni < 2; ++ni) {
#pragma unroll
                for (int r = 0; r < 4; ++r) {
                    const int row = m0 + mloc + mi * 16 + g * 4 + r;
                    const int col = nloc + ni * 16 + c;
                    float v = acc[mi][ni][r] + A.b1[col];
                    A.t1[(long)row * 1536 + col] = f2bf(gelu_exact(v));
                }
            }
        }
    }
    grid.sync();

    // ================= P6: out += t1 @ W2 (split-K=4, atomic; out pre-init = s1 + b2) =================
    for (int vb = bid; vb < 384; vb += 256) {
        const int z = vb / 96;
        mgemm_body(A.t1, A.W2T, A.out, nullptr,
                   (vb % 16) * 64, ((vb / 16) % 6) * 64, 1536, 384, z * 384, z * 384 + 384, 5, tid);
    }
}

extern "C" void kernel_launch(void* const* d_in, const int* in_sizes, int n_in,
                              void* d_out, int out_size, void* d_ws, size_t ws_size,
                              hipStream_t stream) {
    MegaArgs ma;
    ma.s    = (const float*)d_in[0];
    ma.pair = (const float*)d_in[1];
    ma.g_s  = (const float*)d_in[3];
    ma.b_s  = (const float*)d_in[4];
    ma.Wq   = (const float*)d_in[5];
    ma.Wk   = (const float*)d_in[6];
    ma.Wv   = (const float*)d_in[7];
    ma.Wb   = (const float*)d_in[8];
    ma.Wo   = (const float*)d_in[9];
    ma.bo   = (const float*)d_in[10];
    ma.g_f  = (const float*)d_in[11];
    ma.b_f  = (const float*)d_in[12];
    ma.W1   = (const float*)d_in[13];
    ma.b1   = (const float*)d_in[14];
    ma.W2   = (const float*)d_in[15];
    ma.b2   = (const float*)d_in[16];
    ma.out  = (float*)d_out;

    char* w = (char*)d_ws;
    ma.Opart = (ushort*)w; w += 25165824;   // 12*32*1024*32 bf16
    ma.mlb   = (float*)w;  w += 1572864;    // 12*32*1024 f32
    ma.s1    = (float*)w;  w += 1572864;
    ma.qkv   = (ushort*)w; w += 2359296;    // [1024][1152] bf16
    ma.sn    = (ushort*)w; w += 786432;
    ma.attb  = (ushort*)w; w += 786432;
    ma.t1    = (ushort*)w; w += 3145728;    // [1024][1536] bf16
    ma.qkvT  = (ushort*)w; w += 884736;
    ma.WoT   = (ushort*)w; w += 294912;
    ma.W1T   = (ushort*)w; w += 1179648;
    ma.W2T   = (ushort*)w; w += 1179648;

    void* kp[] = { &ma };
    hipLaunchCooperativeKernel(mega_k, dim3(256), dim3(256), kp, 0, stream);
}

// Round 9
// 198.119 us; speedup vs baseline: 2.0430x; 2.0430x over previous
//
#include <hip/hip_runtime.h>
#include <hip/hip_bf16.h>
#include <math.h>

typedef short v8s __attribute__((ext_vector_type(8)));
typedef float v4f __attribute__((ext_vector_type(4)));

#define LSEQ 1024
#define DS 384
#define NH 12
#define HD 32
#define DP 128

static __device__ __forceinline__ ushort f2bf(float f) {
    __hip_bfloat16 h = __float2bfloat16(f);
    return *reinterpret_cast<ushort*>(&h);
}
static __device__ __forceinline__ float bf2f(ushort u) {
    return __uint_as_float(((unsigned)u) << 16);
}
static __device__ __forceinline__ float gelu_exact(float x) {
    return 0.5f * x * (1.0f + erff(x * 0.70710678118654752f));
}

// ==================== prep2: wcvt [0,1728) + LN1 [1728,1984) + s1=s+bo [1984,2368) ====================
__global__ __launch_bounds__(256) void prep2_k(const float* __restrict__ s,
                                               const float* __restrict__ g_s,
                                               const float* __restrict__ b_s,
                                               ushort* __restrict__ sn,
                                               const float* __restrict__ Wq,
                                               const float* __restrict__ Wk,
                                               const float* __restrict__ Wv,
                                               const float* __restrict__ Wo,
                                               const float* __restrict__ W1,
                                               const float* __restrict__ W2,
                                               ushort* __restrict__ qkvT,
                                               ushort* __restrict__ WoT,
                                               ushort* __restrict__ W1T,
                                               ushort* __restrict__ W2T,
                                               const float* __restrict__ bo,
                                               float* __restrict__ s1) {
    __shared__ float tile[32][33];
    const int bid = blockIdx.x;
    const int tid = threadIdx.x;

    if (bid < 1728) {
        int id = bid;
        const float* W; ushort* WT; int Kd, Nd, t;
        if (id < 144)       { W = Wq; WT = qkvT;             Kd = 384;  Nd = 384;  t = id; }
        else if (id < 288)  { W = Wk; WT = qkvT + 384 * 384; Kd = 384;  Nd = 384;  t = id - 144; }
        else if (id < 432)  { W = Wv; WT = qkvT + 768 * 384; Kd = 384;  Nd = 384;  t = id - 288; }
        else if (id < 576)  { W = Wo; WT = WoT;              Kd = 384;  Nd = 384;  t = id - 432; }
        else if (id < 1152) { W = W1; WT = W1T;              Kd = 384;  Nd = 1536; t = id - 576; }
        else                { W = W2; WT = W2T;              Kd = 1536; Nd = 384;  t = id - 1152; }
        const int ktiles = Kd >> 5;
        const int k0 = (t % ktiles) * 32, n0 = (t / ktiles) * 32;
        const int r = tid >> 3, c4 = (tid & 7) * 4;
        float4 v = *reinterpret_cast<const float4*>(W + (long)(k0 + r) * Nd + n0 + c4);
        tile[r][c4 + 0] = v.x; tile[r][c4 + 1] = v.y;
        tile[r][c4 + 2] = v.z; tile[r][c4 + 3] = v.w;
        __syncthreads();
        ushort4 o;
        o.x = f2bf(tile[c4 + 0][r]); o.y = f2bf(tile[c4 + 1][r]);
        o.z = f2bf(tile[c4 + 2][r]); o.w = f2bf(tile[c4 + 3][r]);
        *reinterpret_cast<ushort4*>(WT + (long)(n0 + r) * Kd + k0 + c4) = o;
    } else if (bid < 1984) {
        const int wid = tid >> 6, lane = tid & 63;
        const int row = (bid - 1728) * 4 + wid;
        const float* xr = s + (long)row * DS;
        float v[6];
        float sm = 0.f;
#pragma unroll
        for (int t = 0; t < 6; ++t) { v[t] = xr[lane + t * 64]; sm += v[t]; }
#pragma unroll
        for (int o = 32; o >= 1; o >>= 1) sm += __shfl_xor(sm, o);
        const float mean = sm * (1.f / DS);
        float q = 0.f;
#pragma unroll
        for (int t = 0; t < 6; ++t) { float d = v[t] - mean; q += d * d; }
#pragma unroll
        for (int o = 32; o >= 1; o >>= 1) q += __shfl_xor(q, o);
        const float rs = rsqrtf(q * (1.f / DS) + 1e-5f);
#pragma unroll
        for (int t = 0; t < 6; ++t) {
            int cc = lane + t * 64;
            sn[(long)row * DS + cc] = f2bf((v[t] - mean) * rs * g_s[cc] + b_s[cc]);
        }
    } else {
        const int i4 = ((bid - 1984) * 256 + tid) * 4;
        float4 sv = *reinterpret_cast<const float4*>(s + i4);
        const int col = i4 % DS;
        float4 bv = *reinterpret_cast<const float4*>(bo + col);
        float4 o;
        o.x = sv.x + bv.x; o.y = sv.y + bv.y;
        o.z = sv.z + bv.z; o.w = sv.w + bv.w;
        *reinterpret_cast<float4*>(s1 + i4) = o;
    }
}

// ==================== LayerNorm (LN2): hn bf16 + out_init = x + b2 ====================
__global__ __launch_bounds__(256) void ln_k(const float* __restrict__ x,
                                            const float* __restrict__ g,
                                            const float* __restrict__ b,
                                            ushort* __restrict__ ybf,
                                            float* __restrict__ pre,
                                            const float* __restrict__ pre_bias) {
    const int wid = threadIdx.x >> 6, lane = threadIdx.x & 63;
    const int row = blockIdx.x * 4 + wid;
    const float* xr = x + (long)row * DS;
    float v[6];
    float s = 0.f;
#pragma unroll
    for (int t = 0; t < 6; ++t) { v[t] = xr[lane + t * 64]; s += v[t]; }
#pragma unroll
    for (int o = 32; o >= 1; o >>= 1) s += __shfl_xor(s, o);
    const float mean = s * (1.f / DS);
    float q = 0.f;
#pragma unroll
    for (int t = 0; t < 6; ++t) { float d = v[t] - mean; q += d * d; }
#pragma unroll
    for (int o = 32; o >= 1; o >>= 1) q += __shfl_xor(q, o);
    const float rs = rsqrtf(q * (1.f / DS) + 1e-5f);
#pragma unroll
    for (int t = 0; t < 6; ++t) {
        int c = lane + t * 64;
        ybf[(long)row * DS + c] = f2bf((v[t] - mean) * rs * g[c] + b[c]);
        pre[(long)row * DS + c] = v[t] + pre_bias[c];
    }
}

// ==================== register-resident bf16 MFMA GEMM ====================
// EPI: 1 f32 store (+bias+res) ; 3 bf16 gelu (+bias) ; 4 bf16 store ; 5 f32 atomicAdd
template <int EPI>
__global__ __launch_bounds__(256) void mgemm_k(const ushort* __restrict__ A,
                                               const ushort* __restrict__ BT,
                                               float* __restrict__ Cf,
                                               ushort* __restrict__ Cb,
                                               const float* __restrict__ bias,
                                               const float* __restrict__ res,
                                               int K, int ldc, int ksplit) {
    const int w = threadIdx.x >> 6;
    const int lane = threadIdx.x & 63;
    const int c = lane & 15, g = lane >> 4;
    const int m0 = blockIdx.x * 64 + (w >> 1) * 32;
    const int n0 = blockIdx.y * 64 + (w & 1) * 32;
    const int kc = K / ksplit;
    const int kbeg = blockIdx.z * kc, kend = kbeg + kc;

    v4f acc[2][2];
#pragma unroll
    for (int i = 0; i < 2; ++i)
#pragma unroll
        for (int j = 0; j < 2; ++j) acc[i][j] = (v4f){0.f, 0.f, 0.f, 0.f};

    const ushort* Ap0 = A + (long)(m0 + c) * K + g * 8;
    const ushort* Ap1 = A + (long)(m0 + 16 + c) * K + g * 8;
    const ushort* Bp0 = BT + (long)(n0 + c) * K + g * 8;
    const ushort* Bp1 = BT + (long)(n0 + 16 + c) * K + g * 8;

#pragma unroll 4
    for (int k0 = kbeg; k0 < kend; k0 += 32) {
        v8s a0 = *reinterpret_cast<const v8s*>(Ap0 + k0);
        v8s a1 = *reinterpret_cast<const v8s*>(Ap1 + k0);
        v8s b0 = *reinterpret_cast<const v8s*>(Bp0 + k0);
        v8s b1 = *reinterpret_cast<const v8s*>(Bp1 + k0);
        acc[0][0] = __builtin_amdgcn_mfma_f32_16x16x32_bf16(a0, b0, acc[0][0], 0, 0, 0);
        acc[0][1] = __builtin_amdgcn_mfma_f32_16x16x32_bf16(a0, b1, acc[0][1], 0, 0, 0);
        acc[1][0] = __builtin_amdgcn_mfma_f32_16x16x32_bf16(a1, b0, acc[1][0], 0, 0, 0);
        acc[1][1] = __builtin_amdgcn_mfma_f32_16x16x32_bf16(a1, b1, acc[1][1], 0, 0, 0);
    }

#pragma unroll
    for (int mi = 0; mi < 2; ++mi) {
#pragma unroll
        for (int ni = 0; ni < 2; ++ni) {
#pragma unroll
            for (int r = 0; r < 4; ++r) {
                const int row = m0 + mi * 16 + g * 4 + r;
                const int col = n0 + ni * 16 + c;
                float v = acc[mi][ni][r];
                if (bias) v += bias[col];
                const long idx = (long)row * ldc + col;
                if (EPI == 1) Cf[idx] = v + res[idx];
                else if (EPI == 3) Cb[idx] = f2bf(gelu_exact(v));
                else if (EPI == 4) Cb[idx] = f2bf(v);
                else atomicAdd(&Cf[idx], v);
            }
        }
    }
}

// ==================== fused pair-bias + attention chunk ====================
// grid (32 kc, 32 qb), 128 thr = 2 waves. Pair read: direct per-lane float4 register
// loads (no LDS stage, no vmcnt drains -> compiler pipelines; 8 waves/CU).
__global__ __launch_bounds__(128) void fa2_k(const float* __restrict__ pair,
                                             const float* __restrict__ Wb,
                                             const ushort* __restrict__ qkv,
                                             ushort* __restrict__ Opart,
                                             float* __restrict__ ml) {
    __shared__ ushort BL[32 * 32 * NH];     // bias [q_local][k_local][head]  (24.6 KB)
    __shared__ ushort P[2][16][34];         // per-wave P tile (2.2 KB)

    const int kc = blockIdx.x, qb = blockIdx.y;
    const int q0 = qb * 32, k0 = kc * 32;
    const int tid = threadIdx.x;
    const int w = tid >> 6, lane = tid & 63;
    const int c = lane & 15, g = lane >> 4;
    const float scale = 0.17677669529663688f;

    // ---- Wb fragments (proven pairb layout) ----
    v8s bfrag[4];
#pragma unroll
    for (int t2 = 0; t2 < 4; ++t2) {
#pragma unroll
        for (int j = 0; j < 8; ++j) {
            int p = t2 * 32 + g * 8 + j;
            float wv = (c < NH) ? Wb[p * NH + c] : 0.f;
            bfrag[t2][j] = (short)f2bf(wv);
        }
    }

    // ---- Phase 1: 32 tiles (1 q row x 16 keys x 128 feats), register-direct ----
    // lane (c,g) reads cell = (q_row, k0 + kh*16 + c), feats [t2*32 + g*8, +8)
    const float* srcbase = pair + ((long)(q0 + w * 16) * 1024 + k0 + c) * 128 + g * 8;
#pragma unroll 2
    for (int t = 0; t < 32; ++t) {
        const int ql = t >> 1, kh = t & 1;
        const float* src = srcbase + (long)ql * 131072 + kh * 2048;
        float4 x0[4], x1[4];
#pragma unroll
        for (int t2 = 0; t2 < 4; ++t2) {
            x0[t2] = *reinterpret_cast<const float4*>(src + t2 * 32);
            x1[t2] = *reinterpret_cast<const float4*>(src + t2 * 32 + 4);
        }
        v4f acc = {0.f, 0.f, 0.f, 0.f};
#pragma unroll
        for (int t2 = 0; t2 < 4; ++t2) {
            v8s a;
            a[0] = (short)f2bf(x0[t2].x); a[1] = (short)f2bf(x0[t2].y);
            a[2] = (short)f2bf(x0[t2].z); a[3] = (short)f2bf(x0[t2].w);
            a[4] = (short)f2bf(x1[t2].x); a[5] = (short)f2bf(x1[t2].y);
            a[6] = (short)f2bf(x1[t2].z); a[7] = (short)f2bf(x1[t2].w);
            acc = __builtin_amdgcn_mfma_f32_16x16x32_bf16(a, bfrag[t2], acc, 0, 0, 0);
        }
        // D: row m = key cell (g*4+r), col n = head (c)
        if (c < NH) {
#pragma unroll
            for (int r = 0; r < 4; ++r)
                BL[((w * 16 + ql) * 32 + kh * 16 + g * 4 + r) * NH + c] = f2bf(acc[r]);
        }
    }
    // BL is wave-local (each wave writes/reads only its own 16 q rows) -> no barrier

    // ---- Phase 2: per-head QK^T + bias, max-free exp, PV (scalar V, L2-hot) ----
#pragma unroll 1
    for (int h = 0; h < NH; ++h) {
        const v8s aq = *reinterpret_cast<const v8s*>(
            qkv + (long)(q0 + w * 16 + c) * 1152 + h * 32 + g * 8);

        v4f sfr[2];
#pragma unroll
        for (int nf = 0; nf < 2; ++nf) {
            v8s bk = *reinterpret_cast<const v8s*>(
                qkv + (long)(k0 + nf * 16 + c) * 1152 + 384 + h * 32 + g * 8);
            v4f z = {0.f, 0.f, 0.f, 0.f};
            sfr[nf] = __builtin_amdgcn_mfma_f32_16x16x32_bf16(aq, bk, z, 0, 0, 0);
        }

        float p[2][4];
        float ls[4];
#pragma unroll
        for (int r = 0; r < 4; ++r) ls[r] = 0.f;
#pragma unroll
        for (int nf = 0; nf < 2; ++nf) {
#pragma unroll
            for (int r = 0; r < 4; ++r) {
                const int qr = w * 16 + g * 4 + r;
                float sv = sfr[nf][r] * scale + bf2f(BL[(qr * 32 + nf * 16 + c) * NH + h]);
                float e = __expf(sv);
                p[nf][r] = e;
                ls[r] += e;
            }
        }
#pragma unroll
        for (int r = 0; r < 4; ++r) {
            ls[r] += __shfl_xor(ls[r], 1);
            ls[r] += __shfl_xor(ls[r], 2);
            ls[r] += __shfl_xor(ls[r], 4);
            ls[r] += __shfl_xor(ls[r], 8);
        }

        // P -> LDS
#pragma unroll
        for (int nf = 0; nf < 2; ++nf)
#pragma unroll
            for (int r = 0; r < 4; ++r)
                P[w][g * 4 + r][nf * 16 + c] = f2bf(p[nf][r]);

        const v8s pa = *reinterpret_cast<const v8s*>(&P[w][c][g * 8]);

        v4f oacc[2];
#pragma unroll
        for (int nf2 = 0; nf2 < 2; ++nf2) {
            v8s vb;
#pragma unroll
            for (int j = 0; j < 8; ++j)
                vb[j] = (short)qkv[(long)(k0 + g * 8 + j) * 1152 + 768 + h * 32 + nf2 * 16 + c];
            v4f z = {0.f, 0.f, 0.f, 0.f};
            oacc[nf2] = __builtin_amdgcn_mfma_f32_16x16x32_bf16(pa, vb, z, 0, 0, 0);
        }

        const long base = ((long)(h * 32 + kc) * 1024 + q0 + w * 16 + g * 4);
#pragma unroll
        for (int r = 0; r < 4; ++r) {
            Opart[(base + r) * 32 + c] = f2bf(oacc[0][r]);
            Opart[(base + r) * 32 + 16 + c] = f2bf(oacc[1][r]);
        }
        if (c == 0) {
#pragma unroll
            for (int r = 0; r < 4; ++r)
                ml[base + r] = ls[r];
        }
    }
}

// ==================== combine partial chunks (pure sum) ====================
__global__ __launch_bounds__(256) void combine_k(const ushort* __restrict__ Opart,
                                                 const float* __restrict__ ml,
                                                 ushort* __restrict__ att) {
    const int h = blockIdx.y;
    const int q = blockIdx.x * 64 + (threadIdx.x >> 2);
    const int ds = (threadIdx.x & 3) * 8;

    float lsum = 0.f;
    float O[8];
#pragma unroll
    for (int j = 0; j < 8; ++j) O[j] = 0.f;

    for (int kc = 0; kc < 32; ++kc) {
        const long base = ((long)(h * 32 + kc) * 1024 + q);
        lsum += ml[base];
        v8s ov = *reinterpret_cast<const v8s*>(Opart + base * 32 + ds);
#pragma unroll
        for (int j = 0; j < 8; ++j) O[j] += bf2f((ushort)ov[j]);
    }
    const float inv = 1.f / lsum;
    ushort4 u0, u1;
    u0.x = f2bf(O[0] * inv); u0.y = f2bf(O[1] * inv);
    u0.z = f2bf(O[2] * inv); u0.w = f2bf(O[3] * inv);
    u1.x = f2bf(O[4] * inv); u1.y = f2bf(O[5] * inv);
    u1.z = f2bf(O[6] * inv); u1.w = f2bf(O[7] * inv);
    *reinterpret_cast<ushort4*>(att + (long)q * DS + h * 32 + ds) = u0;
    *reinterpret_cast<ushort4*>(att + (long)q * DS + h * 32 + ds + 4) = u1;
}

extern "C" void kernel_launch(void* const* d_in, const int* in_sizes, int n_in,
                              void* d_out, int out_size, void* d_ws, size_t ws_size,
                              hipStream_t stream) {
    const float* s    = (const float*)d_in[0];
    const float* pair = (const float*)d_in[1];
    const float* g_s = (const float*)d_in[3];
    const float* b_s = (const float*)d_in[4];
    const float* Wq  = (const float*)d_in[5];
    const float* Wk  = (const float*)d_in[6];
    const float* Wv  = (const float*)d_in[7];
    const float* Wb  = (const float*)d_in[8];
    const float* Wo  = (const float*)d_in[9];
    const float* bo  = (const float*)d_in[10];
    const float* g_f = (const float*)d_in[11];
    const float* b_f = (const float*)d_in[12];
    const float* W1  = (const float*)d_in[13];
    const float* b1  = (const float*)d_in[14];
    const float* W2  = (const float*)d_in[15];
    const float* b2  = (const float*)d_in[16];
    float* out = (float*)d_out;

    char* ws = (char*)d_ws;
    ushort* Opart = (ushort*)ws;                       ws += 25165824;  // 12*32*1024*32*2
    float*  mlb   = (float*)ws;                        ws += 1572864;   // 12*32*1024*4
    float*  s1    = (float*)ws;                        ws += 1572864;
    ushort* qkv   = (ushort*)ws;                       ws += 2359296;
    ushort* sn    = (ushort*)ws;                       ws += 786432;
    ushort* hn    = (ushort*)ws;                       ws += 786432;
    ushort* attb  = (ushort*)ws;                       ws += 786432;
    ushort* t1    = (ushort*)ws;                       ws += 3145728;
    ushort* qkvT  = (ushort*)ws;                       ws += 884736;
    ushort* WoT   = (ushort*)ws;                       ws += 294912;
    ushort* W1T   = (ushort*)ws;                       ws += 1179648;
    ushort* W2T   = (ushort*)ws;                       ws += 1179648;

    const dim3 blk(256);

    // 1) prep2: weight cvts + LN1 + s1 = s + bo
    prep2_k<<<dim3(2368), blk, 0, stream>>>(s, g_s, b_s, sn,
                                            Wq, Wk, Wv, Wo, W1, W2,
                                            qkvT, WoT, W1T, W2T, bo, s1);

    // 2) QKV (bf16)
    mgemm_k<4><<<dim3(16, 18, 1), blk, 0, stream>>>(sn, qkvT, nullptr, qkv,
                                                    nullptr, nullptr, 384, 1152, 1);

    // 3) fused pair-bias + attention chunks (register-direct pair stream)
    fa2_k<<<dim3(32, 32), dim3(128), 0, stream>>>(pair, Wb, qkv, Opart, mlb);

    // 4) combine chunks -> attb
    combine_k<<<dim3(16, 12), blk, 0, stream>>>(Opart, mlb, attb);

    // 5) s1 += att @ Wo (split-K=2, atomic; s1 pre-init = s + bo)
    mgemm_k<5><<<dim3(16, 6, 2), blk, 0, stream>>>(attb, WoT, s1, nullptr,
                                                   nullptr, nullptr, 384, 384, 2);

    // 6) LN2 -> hn (bf16) ; out = s1 + b2
    ln_k<<<dim3(256), blk, 0, stream>>>(s1, g_f, b_f, hn, out, b2);

    // 7) t1 = gelu(hn @ W1 + b1)
    mgemm_k<3><<<dim3(16, 24, 1), blk, 0, stream>>>(hn, W1T, nullptr, t1,
                                                    b1, nullptr, 384, 1536, 1);

    // 8) out += t1 @ W2 (split-K=2, atomic; out pre-init = s1 + b2)
    mgemm_k<5><<<dim3(16, 6, 2), blk, 0, stream>>>(t1, W2T, out, nullptr,
                                                   nullptr, nullptr, 1536, 384, 2);
}